// Round 3
// baseline (243.683 us; speedup 1.0000x reference)
//
#include <hip/hip_runtime.h>

#define BLANK 36
#define NEG -1e30f
#define CC 37
#define PFD 8   // prefetch depth in the alpha recurrence

__device__ __forceinline__ float logaddexp_f(float a, float b) {
    float m = fmaxf(a, b);
    float d = fabsf(a - b);
    return m + __logf(1.0f + __expf(-d));
}

// ---------------- Kernel A: per-(b,t) logsumexp over C=37 classes ----------
// Wave-cooperative: each wave stages 64 rows (2368 floats) into LDS with
// coalesced float4 loads, then each lane reduces its own row from LDS.
// Per-wave LDS tile -> no __syncthreads needed (wave is lockstep).
__global__ __launch_bounds__(256) void lse_kernel(
    const float* __restrict__ logits,  // [N, C] flat
    float*       __restrict__ denom,   // [N]
    int N)
{
    __shared__ float lds[256 * CC];            // 4 waves * 2368 floats
    const int lane  = threadIdx.x & 63;
    const int wib   = threadIdx.x >> 6;        // wave in block
    const int wave  = blockIdx.x * 4 + wib;    // global wave id
    const long long row0 = (long long)wave * 64;
    if (row0 >= N) return;

    const int wbase = wib * 64 * CC;           // float offset of this wave's tile

    // ---- stage 64*37 floats = 592 float4, coalesced ----
    const float4* src4 = (const float4*)(logits + row0 * CC);  // 16B-aligned: row0*CC*4 % 16 == 0
    const long long n4_remaining = ((long long)N * CC - row0 * CC) / 4;
    float4* lds4 = (float4*)(lds + wbase);
    #pragma unroll
    for (int k = 0; k < 10; ++k) {
        const int idx = k * 64 + lane;
        if (idx < 592 && idx < n4_remaining) lds4[idx] = src4[idx];
    }
    // wave-internal LDS visibility: compiler inserts lgkmcnt wait before reads;
    // same wave wrote the data, so no barrier required.
    __builtin_amdgcn_s_waitcnt(0);  // vmcnt(0) & lgkmcnt(0): all writes landed

    const long long row = row0 + lane;
    if (row >= N) return;
    const float* x = lds + wbase + lane * CC;
    float m = x[0];
    #pragma unroll
    for (int c = 1; c < CC; ++c) m = fmaxf(m, x[c]);
    float s = 0.0f;
    #pragma unroll
    for (int c = 0; c < CC; ++c) s += __expf(x[c] - m);
    denom[row] = m + __logf(s);
}

// ---------------- Kernel B: alpha recurrence, one wave per sample ----------
// Depth-PFD register prefetch: the gather x[t][ext_s] and denom[t] for step
// t+PFD are issued while step t's chain executes, hiding ~600+ cyc of cache
// latency behind 8 chain-lengths.
__global__ __launch_bounds__(256) void ctc_alpha3_kernel(
    const float* __restrict__ logits,        // [B, T, C]
    const float* __restrict__ denom,         // [B, T]
    const int*   __restrict__ targets,       // [B * L]
    const int*   __restrict__ input_lengths, // [B]
    const int*   __restrict__ target_lengths,// [B]
    float*       __restrict__ per_sample,    // [B]
    int B, int T, int L)
{
    const int wave = (int)((blockIdx.x * blockDim.x + threadIdx.x) >> 6);
    const int lane = threadIdx.x & 63;
    if (wave >= B) return;
    const int b = wave;
    const int S = 2 * L + 1;

    const int tlen = target_lengths[b];
    const int ilen = input_lengths[b];
    const int end_idx = 2 * tlen;

    int ext_s = BLANK;  // always < CC, so gathers are in-bounds for every lane
    if (lane < S && (lane & 1)) ext_s = targets[b * L + (lane >> 1)];
    const int ext_sm2 = __shfl_up(ext_s, 2);
    const bool skip_ok = (lane < S) && (lane >= 2) && (ext_s != BLANK) && (ext_s != ext_sm2);
    const bool valid = lane < (2 * tlen + 1);

    const float* lg = logits + (size_t)b * T * CC + ext_s;  // gather column baked in
    const float* dn = denom + (size_t)b * T;

    // ---- preload slots t = 0..PFD-1 ----
    float xb[PFD], db[PFD];
    #pragma unroll
    for (int k = 0; k < PFD; ++k) {
        const int tt = (k < T) ? k : (T - 1);
        xb[k] = lg[(size_t)tt * CC];
        db[k] = dn[tt];
    }

    // ---- t = 0 ----
    float final_v = NEG;
    float alpha = (valid && lane <= 1) ? (xb[0] - db[0]) : NEG;
    if (ilen == 1) {
        const float e1 = __shfl(alpha, end_idx);
        const float e2 = __shfl(alpha, end_idx - 1);
        final_v = logaddexp_f(e1, e2);
    }
    // refill slot 0 with t = PFD
    if (PFD < T) { xb[0] = lg[(size_t)PFD * CC]; db[0] = dn[PFD]; }

    int t = 1;
    // ---- main loop: prefetch t+PFD while computing t ----
    #pragma unroll PFD
    for (; t < T - PFD; ++t) {
        const int slot = t & (PFD - 1);
        const float x = xb[slot], d = db[slot];
        xb[slot] = lg[(size_t)(t + PFD) * CC];
        db[slot] = dn[t + PFD];

        float a1 = __shfl_up(alpha, 1);
        if (lane == 0) a1 = NEG;
        float a2 = __shfl_up(alpha, 2);
        if (!skip_ok) a2 = NEG;

        const float m = fmaxf(fmaxf(alpha, a1), a2);
        const float s = __expf(alpha - m) + __expf(a1 - m) + __expf(a2 - m);
        const float na = m + __logf(s) + (x - d);
        alpha = valid ? na : NEG;

        if (ilen == t + 1) {  // wave-uniform
            const float e1 = __shfl(alpha, end_idx);
            const float e2 = __shfl(alpha, end_idx - 1);
            final_v = logaddexp_f(e1, e2);
        }
    }
    // ---- tail: no prefetch ----
    #pragma unroll PFD
    for (; t < T; ++t) {
        const int slot = t & (PFD - 1);
        const float x = xb[slot], d = db[slot];

        float a1 = __shfl_up(alpha, 1);
        if (lane == 0) a1 = NEG;
        float a2 = __shfl_up(alpha, 2);
        if (!skip_ok) a2 = NEG;

        const float m = fmaxf(fmaxf(alpha, a1), a2);
        const float s = __expf(alpha - m) + __expf(a1 - m) + __expf(a2 - m);
        const float na = m + __logf(s) + (x - d);
        alpha = valid ? na : NEG;

        if (ilen == t + 1) {
            const float e1 = __shfl(alpha, end_idx);
            const float e2 = __shfl(alpha, end_idx - 1);
            final_v = logaddexp_f(e1, e2);
        }
    }

    if (lane == 0) per_sample[b] = -final_v / (float)tlen;
}

// ---------------- Fallback: monolithic kernel (ws too small) ---------------
__global__ __launch_bounds__(256) void ctc_alpha_mono_kernel(
    const float* __restrict__ logits,
    const int*   __restrict__ targets,
    const int*   __restrict__ input_lengths,
    const int*   __restrict__ target_lengths,
    float*       __restrict__ per_sample,
    int B, int T, int L)
{
    const int wave = (int)((blockIdx.x * blockDim.x + threadIdx.x) >> 6);
    const int lane = threadIdx.x & 63;
    if (wave >= B) return;
    const int b = wave;
    const int S = 2 * L + 1;
    const int tlen = target_lengths[b];
    const int ilen = input_lengths[b];
    const int end_idx = 2 * tlen;
    int ext_s = BLANK;
    if (lane < S && (lane & 1)) ext_s = targets[b * L + (lane >> 1)];
    const int ext_sm2 = __shfl_up(ext_s, 2);
    const bool skip_ok = (lane < S) && (lane >= 2) && (ext_s != BLANK) && (ext_s != ext_sm2);
    const bool valid = lane < (2 * tlen + 1);
    const float* lg = logits + (size_t)b * T * CC;
    float alpha = NEG, final_v = NEG;
    for (int t = 0; t < T; ++t) {
        float x = (lane < CC) ? lg[t * CC + lane] : -3.0e38f;
        float mx = x;
        #pragma unroll
        for (int o = 32; o > 0; o >>= 1) mx = fmaxf(mx, __shfl_xor(mx, o));
        float e = (lane < CC) ? __expf(x - mx) : 0.0f;
        float se = e;
        #pragma unroll
        for (int o = 32; o > 0; o >>= 1) se += __shfl_xor(se, o);
        const float lp = x - mx - __logf(se);
        const float lpe = __shfl(lp, ext_s);
        float newa;
        if (t == 0) {
            newa = (lane <= 1) ? lpe : NEG;
        } else {
            float a1 = __shfl_up(alpha, 1);
            if (lane == 0) a1 = NEG;
            float a2 = __shfl_up(alpha, 2);
            if (!skip_ok) a2 = NEG;
            newa = logaddexp_f(logaddexp_f(alpha, a1), a2) + lpe;
        }
        if (!valid) newa = NEG;
        alpha = newa;
        if (ilen == t + 1) {
            const float e1 = __shfl(alpha, end_idx);
            const float e2 = __shfl(alpha, end_idx - 1);
            final_v = logaddexp_f(e1, e2);
        }
    }
    if (lane == 0) per_sample[b] = -final_v / (float)tlen;
}

// ---------------- Deterministic mean over B samples ------------------------
__global__ __launch_bounds__(256) void reduce_mean_kernel(
    const float* __restrict__ ps, float* __restrict__ out, int B)
{
    float s = 0.0f;
    for (int i = threadIdx.x; i < B; i += 256) s += ps[i];
    #pragma unroll
    for (int o = 32; o > 0; o >>= 1) s += __shfl_xor(s, o);
    __shared__ float sm[4];
    const int w = threadIdx.x >> 6, l = threadIdx.x & 63;
    if (l == 0) sm[w] = s;
    __syncthreads();
    if (threadIdx.x == 0) {
        out[0] = (sm[0] + sm[1] + sm[2] + sm[3]) / (float)B;
    }
}

extern "C" void kernel_launch(void* const* d_in, const int* in_sizes, int n_in,
                              void* d_out, int out_size, void* d_ws, size_t ws_size,
                              hipStream_t stream) {
    const float* logits         = (const float*)d_in[0];
    const int*   targets        = (const int*)d_in[1];
    const int*   input_lengths  = (const int*)d_in[2];
    const int*   target_lengths = (const int*)d_in[3];

    const int B = in_sizes[2];
    const int L = in_sizes[1] / B;
    const int T = in_sizes[0] / (B * CC);
    const int N = B * T;

    float* per_sample = (float*)d_ws;          // B floats
    float* denom      = per_sample + B;        // B*T floats
    float* out        = (float*)d_out;

    const size_t ws_needed = (size_t)(B + N) * sizeof(float);
    const int nblocks_alpha = (B * 64 + 255) / 256;

    if (ws_size >= ws_needed && T > 2 * PFD) {
        const int nwaves = (N + 63) / 64;
        lse_kernel<<<(nwaves + 3) / 4, 256, 0, stream>>>(logits, denom, N);
        ctc_alpha3_kernel<<<nblocks_alpha, 256, 0, stream>>>(
            logits, denom, targets, input_lengths, target_lengths, per_sample, B, T, L);
    } else {
        ctc_alpha_mono_kernel<<<nblocks_alpha, 256, 0, stream>>>(
            logits, targets, input_lengths, target_lengths, per_sample, B, T, L);
    }
    reduce_mean_kernel<<<1, 256, 0, stream>>>(per_sample, out, B);
}

// Round 4
// 203.039 us; speedup vs baseline: 1.2002x; 1.2002x over previous
//
#include <hip/hip_runtime.h>

#define BLANK 36
#define NEG -1e30f
#define CC 37
#define PFD 8   // prefetch depth in the alpha recurrence

__device__ __forceinline__ float logaddexp_f(float a, float b) {
    float m = fmaxf(a, b);
    float d = fabsf(a - b);
    return m + __logf(1.0f + __expf(-d));
}

// ---------------- Kernel A: per-(b,t) logsumexp over C=37 classes ----------
// Wave-cooperative: each wave stages 64 rows (2368 floats) into LDS with
// coalesced float4 loads, then each lane reduces its own row from LDS.
// LDS row stride 37 floats -> bank = (lane*5+c)%32, conflict-free (5 coprime 32).
__global__ __launch_bounds__(256) void lse_kernel(
    const float* __restrict__ logits,  // [N, C] flat
    float*       __restrict__ denom,   // [N]
    int N)
{
    __shared__ float lds[256 * CC];            // 4 waves * 2368 floats
    const int lane  = threadIdx.x & 63;
    const int wib   = threadIdx.x >> 6;        // wave in block
    const int wave  = blockIdx.x * 4 + wib;    // global wave id
    const long long row0 = (long long)wave * 64;
    if (row0 >= N) return;

    const int wbase = wib * 64 * CC;

    // ---- stage 64*37 floats = 592 float4, coalesced ----
    const float4* src4 = (const float4*)(logits + row0 * CC);
    const long long n4_remaining = ((long long)N * CC - row0 * CC) / 4;
    float4* lds4 = (float4*)(lds + wbase);
    #pragma unroll
    for (int k = 0; k < 10; ++k) {
        const int idx = k * 64 + lane;
        if (idx < 592 && idx < n4_remaining) lds4[idx] = src4[idx];
    }
    __builtin_amdgcn_s_waitcnt(0);  // all staging writes landed (wave-internal)

    const long long row = row0 + lane;
    if (row >= N) return;
    const float* x = lds + wbase + lane * CC;
    float m = x[0];
    #pragma unroll
    for (int c = 1; c < CC; ++c) m = fmaxf(m, x[c]);
    float s = 0.0f;
    #pragma unroll
    for (int c = 0; c < CC; ++c) s += __expf(x[c] - m);
    denom[row] = m + __logf(s);
}

// ---------------- Kernel B: alpha recurrence, one wave per sample ----------
// Depth-PFD register prefetch hides L2-miss latency. final_ll is NOT in the
// loop: each lane captures its own alpha when t+1==ilen (one cndmask), and
// the cross-lane shuffles + logaddexp run once after the loop. This keeps the
// unrolled loop body free of alpha-dependent shuffles/exp/log beyond the
// recurrence itself (the R3 regression).
__global__ __launch_bounds__(256) void ctc_alpha4_kernel(
    const float* __restrict__ logits,        // [B, T, C]
    const float* __restrict__ denom,         // [B, T]
    const int*   __restrict__ targets,       // [B * L]
    const int*   __restrict__ input_lengths, // [B]
    const int*   __restrict__ target_lengths,// [B]
    float*       __restrict__ per_sample,    // [B]
    int B, int T, int L)
{
    const int wave = (int)((blockIdx.x * blockDim.x + threadIdx.x) >> 6);
    const int lane = threadIdx.x & 63;
    if (wave >= B) return;
    const int b = wave;
    const int S = 2 * L + 1;

    const int tlen = target_lengths[b];
    const int ilen = input_lengths[b];
    const int end_idx = 2 * tlen;

    int ext_s = BLANK;  // always < CC, gathers in-bounds for every lane
    if (lane < S && (lane & 1)) ext_s = targets[b * L + (lane >> 1)];
    const int ext_sm2 = __shfl_up(ext_s, 2);
    const bool skip_ok = (lane < S) && (lane >= 2) && (ext_s != BLANK) && (ext_s != ext_sm2);
    const bool valid = lane < (2 * tlen + 1);

    const float* lg = logits + (size_t)b * T * CC + ext_s;  // gather column baked in
    const float* dn = denom + (size_t)b * T;

    // ---- preload slots t = 0..PFD-1 ----
    float xb[PFD], db[PFD];
    #pragma unroll
    for (int k = 0; k < PFD; ++k) {
        xb[k] = lg[(size_t)k * CC];
        db[k] = dn[k];
    }

    // ---- t = 0 ----
    float cap = NEG;
    float alpha = (valid && lane <= 1) ? (xb[0] - db[0]) : NEG;
    if (ilen == 1) cap = alpha;
    if (PFD < T) { xb[0] = lg[(size_t)PFD * CC]; db[0] = dn[PFD]; }

    int t = 1;
    // ---- main loop: prefetch t+PFD while computing t ----
    #pragma unroll PFD
    for (; t < T - PFD; ++t) {
        const int slot = t & (PFD - 1);
        const float x = xb[slot], d = db[slot];
        xb[slot] = lg[(size_t)(t + PFD) * CC];
        db[slot] = dn[t + PFD];

        float a1 = __shfl_up(alpha, 1);
        if (lane == 0) a1 = NEG;
        float a2 = __shfl_up(alpha, 2);
        if (!skip_ok) a2 = NEG;

        const float m = fmaxf(fmaxf(alpha, a1), a2);
        const float s = __expf(alpha - m) + __expf(a1 - m) + __expf(a2 - m);
        const float na = m + __logf(s) + (x - d);
        alpha = valid ? na : NEG;
        cap = (ilen == t + 1) ? alpha : cap;   // per-lane capture, no shuffles
    }
    // ---- tail: consume remaining slots, no refill ----
    #pragma unroll PFD
    for (; t < T; ++t) {
        const int slot = t & (PFD - 1);
        const float x = xb[slot], d = db[slot];

        float a1 = __shfl_up(alpha, 1);
        if (lane == 0) a1 = NEG;
        float a2 = __shfl_up(alpha, 2);
        if (!skip_ok) a2 = NEG;

        const float m = fmaxf(fmaxf(alpha, a1), a2);
        const float s = __expf(alpha - m) + __expf(a1 - m) + __expf(a2 - m);
        const float na = m + __logf(s) + (x - d);
        alpha = valid ? na : NEG;
        cap = (ilen == t + 1) ? alpha : cap;
    }

    // ---- final_ll once, after the loop ----
    const float e1 = __shfl(cap, end_idx);
    const float e2 = __shfl(cap, end_idx - 1);   // end_idx==0 wraps to lane 63 -> cap=NEG there: harmless
    const float final_v = logaddexp_f(e1, e2);

    if (lane == 0) per_sample[b] = -final_v / (float)tlen;
}

// ---------------- Fallback: monolithic kernel (ws too small) ---------------
__global__ __launch_bounds__(256) void ctc_alpha_mono_kernel(
    const float* __restrict__ logits,
    const int*   __restrict__ targets,
    const int*   __restrict__ input_lengths,
    const int*   __restrict__ target_lengths,
    float*       __restrict__ per_sample,
    int B, int T, int L)
{
    const int wave = (int)((blockIdx.x * blockDim.x + threadIdx.x) >> 6);
    const int lane = threadIdx.x & 63;
    if (wave >= B) return;
    const int b = wave;
    const int S = 2 * L + 1;
    const int tlen = target_lengths[b];
    const int ilen = input_lengths[b];
    const int end_idx = 2 * tlen;
    int ext_s = BLANK;
    if (lane < S && (lane & 1)) ext_s = targets[b * L + (lane >> 1)];
    const int ext_sm2 = __shfl_up(ext_s, 2);
    const bool skip_ok = (lane < S) && (lane >= 2) && (ext_s != BLANK) && (ext_s != ext_sm2);
    const bool valid = lane < (2 * tlen + 1);
    const float* lg = logits + (size_t)b * T * CC;
    float alpha = NEG, final_v = NEG;
    for (int t = 0; t < T; ++t) {
        float x = (lane < CC) ? lg[t * CC + lane] : -3.0e38f;
        float mx = x;
        #pragma unroll
        for (int o = 32; o > 0; o >>= 1) mx = fmaxf(mx, __shfl_xor(mx, o));
        float e = (lane < CC) ? __expf(x - mx) : 0.0f;
        float se = e;
        #pragma unroll
        for (int o = 32; o > 0; o >>= 1) se += __shfl_xor(se, o);
        const float lp = x - mx - __logf(se);
        const float lpe = __shfl(lp, ext_s);
        float newa;
        if (t == 0) {
            newa = (lane <= 1) ? lpe : NEG;
        } else {
            float a1 = __shfl_up(alpha, 1);
            if (lane == 0) a1 = NEG;
            float a2 = __shfl_up(alpha, 2);
            if (!skip_ok) a2 = NEG;
            newa = logaddexp_f(logaddexp_f(alpha, a1), a2) + lpe;
        }
        if (!valid) newa = NEG;
        alpha = newa;
        if (ilen == t + 1) {
            const float e1 = __shfl(alpha, end_idx);
            const float e2 = __shfl(alpha, end_idx - 1);
            final_v = logaddexp_f(e1, e2);
        }
    }
    if (lane == 0) per_sample[b] = -final_v / (float)tlen;
}

// ---------------- Deterministic mean over B samples ------------------------
__global__ __launch_bounds__(256) void reduce_mean_kernel(
    const float* __restrict__ ps, float* __restrict__ out, int B)
{
    float s = 0.0f;
    for (int i = threadIdx.x; i < B; i += 256) s += ps[i];
    #pragma unroll
    for (int o = 32; o > 0; o >>= 1) s += __shfl_xor(s, o);
    __shared__ float sm[4];
    const int w = threadIdx.x >> 6, l = threadIdx.x & 63;
    if (l == 0) sm[w] = s;
    __syncthreads();
    if (threadIdx.x == 0) {
        out[0] = (sm[0] + sm[1] + sm[2] + sm[3]) / (float)B;
    }
}

extern "C" void kernel_launch(void* const* d_in, const int* in_sizes, int n_in,
                              void* d_out, int out_size, void* d_ws, size_t ws_size,
                              hipStream_t stream) {
    const float* logits         = (const float*)d_in[0];
    const int*   targets        = (const int*)d_in[1];
    const int*   input_lengths  = (const int*)d_in[2];
    const int*   target_lengths = (const int*)d_in[3];

    const int B = in_sizes[2];
    const int L = in_sizes[1] / B;
    const int T = in_sizes[0] / (B * CC);
    const int N = B * T;

    float* per_sample = (float*)d_ws;          // B floats
    float* denom      = per_sample + B;        // B*T floats
    float* out        = (float*)d_out;

    const size_t ws_needed = (size_t)(B + N) * sizeof(float);
    const int nblocks_alpha = (B * 64 + 255) / 256;

    if (ws_size >= ws_needed && T > 2 * PFD) {
        const int nwaves = (N + 63) / 64;
        lse_kernel<<<(nwaves + 3) / 4, 256, 0, stream>>>(logits, denom, N);
        ctc_alpha4_kernel<<<nblocks_alpha, 256, 0, stream>>>(
            logits, denom, targets, input_lengths, target_lengths, per_sample, B, T, L);
    } else {
        ctc_alpha_mono_kernel<<<nblocks_alpha, 256, 0, stream>>>(
            logits, targets, input_lengths, target_lengths, per_sample, B, T, L);
    }
    reduce_mean_kernel<<<1, 256, 0, stream>>>(per_sample, out, B);
}

// Round 5
// 166.385 us; speedup vs baseline: 1.4646x; 1.2203x over previous
//
#include <hip/hip_runtime.h>

#define BLANK 36
#define NEG -1e30f
#define CC 37

__device__ __forceinline__ float logaddexp_f(float a, float b) {
    float m = fmaxf(a, b);
    float d = fabsf(a - b);
    return m + __logf(1.0f + __expf(-d));
}

// ============ FAST PATH ====================================================
// Kernel A: logsumexp over C=37 + transposed pre-subtracted output.
// trans[b][c][t] = logits[b,t,c] - LSE(logits[b,t,:]).
// Each wave: 64 consecutive rows (t-values), all in one sample (T%64==0).
// Coalesced float4 staging into LDS; per-lane row reduce (stride-37 LDS reads
// = 2-way bank aliasing = free); 37 coalesced 256B stores.
__global__ __launch_bounds__(256) void lse_transpose_kernel(
    const float* __restrict__ logits,  // [B*T, C] flat
    float*       __restrict__ trans,   // [B, C, T]
    int T, long long N)                // N = B*T, N%64==0, T%64==0
{
    __shared__ float lds[256 * CC];
    const int lane = threadIdx.x & 63;
    const int wib  = threadIdx.x >> 6;
    const long long wave = (long long)blockIdx.x * 4 + wib;
    const long long row0 = wave * 64;
    if (row0 >= N) return;

    const int wbase = wib * 64 * CC;
    const float4* src4 = (const float4*)(logits + row0 * CC);
    float4* lds4 = (float4*)(lds + wbase);
    #pragma unroll
    for (int k = 0; k < 10; ++k) {
        const int idx = k * 64 + lane;
        if (idx < 592) lds4[idx] = src4[idx];   // 64*37/4 = 592 float4
    }
    __builtin_amdgcn_s_waitcnt(0);  // staging landed (wave-internal, no barrier)

    // my row -> registers (static indices only)
    const float* x = lds + wbase + lane * CC;
    float xr[CC];
    #pragma unroll
    for (int c = 0; c < CC; ++c) xr[c] = x[c];
    float m = xr[0];
    #pragma unroll
    for (int c = 1; c < CC; ++c) m = fmaxf(m, xr[c]);
    float s = 0.0f;
    #pragma unroll
    for (int c = 0; c < CC; ++c) s += __expf(xr[c] - m);
    const float den = m + __logf(s);

    // transposed store: all 64 rows share b (T%64==0)
    const long long b  = row0 / T;              // wave-uniform
    const int       t0 = (int)(row0 - b * T);   // wave-uniform
    float* dst = trans + (b * CC) * (long long)T + t0 + lane;
    #pragma unroll
    for (int c = 0; c < CC; ++c) dst[(size_t)c * T] = xr[c] - den;
}

// Kernel B: alpha recurrence, one wave per sample. lpe(t) = col[t] streamed
// with float4 loads through three NAMED register buffers (no dynamic
// indexing -> no scratch; the R4 failure). 12-step static lookahead.
__global__ __launch_bounds__(256) void ctc_alpha5_kernel(
    const float* __restrict__ trans,         // [B, C, T]
    const int*   __restrict__ targets,       // [B * L]
    const int*   __restrict__ input_lengths, // [B]
    const int*   __restrict__ target_lengths,// [B]
    float*       __restrict__ per_sample,    // [B]
    int B, int T, int L)
{
    const int wave = (int)((blockIdx.x * blockDim.x + threadIdx.x) >> 6);
    const int lane = threadIdx.x & 63;
    if (wave >= B) return;
    const int b = wave;
    const int S = 2 * L + 1;

    const int tlen = target_lengths[b];
    const int ilen = input_lengths[b];
    const int end_idx = 2 * tlen;

    int ext_s = BLANK;  // < CC always -> in-bounds for every lane
    if (lane < S && (lane & 1)) ext_s = targets[b * L + (lane >> 1)];
    const int ext_sm2 = __shfl_up(ext_s, 2);
    const bool skip_ok = (lane < S) && (lane >= 2) && (ext_s != BLANK) && (ext_s != ext_sm2);
    const bool valid = lane < (2 * tlen + 1);

    const float* col = trans + ((size_t)b * CC + ext_s) * T;  // my lpe column

    float alpha = NEG, cap = NEG;

    auto STEP = [&](float lpe, int tt) {
        float a1 = __shfl_up(alpha, 1);
        a1 = (lane == 0) ? NEG : a1;
        float a2 = __shfl_up(alpha, 2);
        a2 = skip_ok ? a2 : NEG;
        const float mm = fmaxf(fmaxf(alpha, a1), a2);
        const float ss = __expf(alpha - mm) + __expf(a1 - mm) + __expf(a2 - mm);
        alpha = valid ? (mm + __logf(ss) + lpe) : NEG;
        cap = (ilen == tt + 1) ? alpha : cap;   // per-lane capture, off chain
    };

    // preload t=0..11 (16B-aligned: col base multiple of T*4, T%64==0)
    float4 c1 = *(const float4*)(col + 0);
    float4 c2 = *(const float4*)(col + 4);
    float4 c0 = *(const float4*)(col + 8);

    // peeled group 0 (t=0..3), refill 12..15
    {
        float4 pf = *(const float4*)(col + 12);
        alpha = (valid && lane <= 1) ? c1.x : NEG;     // t = 0 init
        cap = (ilen == 1) ? alpha : cap;
        STEP(c1.y, 1); STEP(c1.z, 2); STEP(c1.w, 3);
        c1 = c2; c2 = c0; c0 = pf;
    }

    int t = 4;
    for (; t + 12 < T; t += 4) {
        float4 pf = *(const float4*)(col + t + 12);
        STEP(c1.x, t); STEP(c1.y, t + 1); STEP(c1.z, t + 2); STEP(c1.w, t + 3);
        c1 = c2; c2 = c0; c0 = pf;
    }
    // tail: 3 buffered groups, no refill
    STEP(c1.x, t); STEP(c1.y, t + 1); STEP(c1.z, t + 2); STEP(c1.w, t + 3); t += 4;
    STEP(c2.x, t); STEP(c2.y, t + 1); STEP(c2.z, t + 2); STEP(c2.w, t + 3); t += 4;
    STEP(c0.x, t); STEP(c0.y, t + 1); STEP(c0.z, t + 2); STEP(c0.w, t + 3);

    const float e1 = __shfl(cap, end_idx);
    const float e2 = __shfl(cap, end_idx - 1);
    const float final_v = logaddexp_f(e1, e2);
    if (lane == 0) per_sample[b] = -final_v / (float)tlen;
}

// ============ FALLBACK PATH (proven R2 kernels) ============================
__global__ __launch_bounds__(256) void lse_kernel(
    const float* __restrict__ logits, float* __restrict__ denom, int N)
{
    __shared__ float lds[256 * CC];
    const int lane = threadIdx.x & 63;
    const int wib  = threadIdx.x >> 6;
    const int wave = blockIdx.x * 4 + wib;
    const long long row0 = (long long)wave * 64;
    if (row0 >= N) return;
    const int wbase = wib * 64 * CC;
    const float4* src4 = (const float4*)(logits + row0 * CC);
    const long long n4_remaining = ((long long)N * CC - row0 * CC) / 4;
    float4* lds4 = (float4*)(lds + wbase);
    #pragma unroll
    for (int k = 0; k < 10; ++k) {
        const int idx = k * 64 + lane;
        if (idx < 592 && idx < n4_remaining) lds4[idx] = src4[idx];
    }
    __builtin_amdgcn_s_waitcnt(0);
    const long long row = row0 + lane;
    if (row >= N) return;
    const float* x = lds + wbase + lane * CC;
    float m = x[0];
    #pragma unroll
    for (int c = 1; c < CC; ++c) m = fmaxf(m, x[c]);
    float s = 0.0f;
    #pragma unroll
    for (int c = 0; c < CC; ++c) s += __expf(x[c] - m);
    denom[row] = m + __logf(s);
}

__global__ __launch_bounds__(256) void ctc_alpha2_kernel(
    const float* __restrict__ logits, const float* __restrict__ denom,
    const int* __restrict__ targets, const int* __restrict__ input_lengths,
    const int* __restrict__ target_lengths, float* __restrict__ per_sample,
    int B, int T, int L)
{
    const int wave = (int)((blockIdx.x * blockDim.x + threadIdx.x) >> 6);
    const int lane = threadIdx.x & 63;
    if (wave >= B) return;
    const int b = wave;
    const int S = 2 * L + 1;
    const int tlen = target_lengths[b];
    const int ilen = input_lengths[b];
    const int end_idx = 2 * tlen;
    int ext_s = BLANK;
    if (lane < S && (lane & 1)) ext_s = targets[b * L + (lane >> 1)];
    const int ext_sm2 = __shfl_up(ext_s, 2);
    const bool skip_ok = (lane < S) && (lane >= 2) && (ext_s != BLANK) && (ext_s != ext_sm2);
    const bool valid = lane < (2 * tlen + 1);
    const float* lg = logits + (size_t)b * T * CC;
    const float* dn = denom + (size_t)b * T;
    float x_cur = lg[ext_s];
    float d_cur = dn[0];
    float x_nx = (T > 1) ? lg[CC + ext_s] : 0.0f;
    float d_nx = (T > 1) ? dn[1] : 0.0f;
    float final_v = NEG;
    float alpha = (valid && lane <= 1) ? (x_cur - d_cur) : NEG;
    if (ilen == 1) {
        const float e1 = __shfl(alpha, end_idx);
        const float e2 = __shfl(alpha, end_idx - 1);
        final_v = logaddexp_f(e1, e2);
    }
    for (int tt = 1; tt < T; ++tt) {
        x_cur = x_nx; d_cur = d_nx;
        if (tt + 1 < T) {
            x_nx = lg[(size_t)(tt + 1) * CC + ext_s];
            d_nx = dn[tt + 1];
        }
        const float lpe = x_cur - d_cur;
        float a1 = __shfl_up(alpha, 1);
        if (lane == 0) a1 = NEG;
        float a2 = __shfl_up(alpha, 2);
        if (!skip_ok) a2 = NEG;
        const float m = fmaxf(fmaxf(alpha, a1), a2);
        const float s = __expf(alpha - m) + __expf(a1 - m) + __expf(a2 - m);
        const float na = m + __logf(s) + lpe;
        alpha = valid ? na : NEG;
        if (ilen == tt + 1) {
            const float e1 = __shfl(alpha, end_idx);
            const float e2 = __shfl(alpha, end_idx - 1);
            final_v = logaddexp_f(e1, e2);
        }
    }
    if (lane == 0) per_sample[b] = -final_v / (float)tlen;
}

__global__ __launch_bounds__(256) void ctc_alpha_mono_kernel(
    const float* __restrict__ logits, const int* __restrict__ targets,
    const int* __restrict__ input_lengths, const int* __restrict__ target_lengths,
    float* __restrict__ per_sample, int B, int T, int L)
{
    const int wave = (int)((blockIdx.x * blockDim.x + threadIdx.x) >> 6);
    const int lane = threadIdx.x & 63;
    if (wave >= B) return;
    const int b = wave;
    const int S = 2 * L + 1;
    const int tlen = target_lengths[b];
    const int ilen = input_lengths[b];
    const int end_idx = 2 * tlen;
    int ext_s = BLANK;
    if (lane < S && (lane & 1)) ext_s = targets[b * L + (lane >> 1)];
    const int ext_sm2 = __shfl_up(ext_s, 2);
    const bool skip_ok = (lane < S) && (lane >= 2) && (ext_s != BLANK) && (ext_s != ext_sm2);
    const bool valid = lane < (2 * tlen + 1);
    const float* lg = logits + (size_t)b * T * CC;
    float alpha = NEG, final_v = NEG;
    for (int t = 0; t < T; ++t) {
        float x = (lane < CC) ? lg[t * CC + lane] : -3.0e38f;
        float mx = x;
        #pragma unroll
        for (int o = 32; o > 0; o >>= 1) mx = fmaxf(mx, __shfl_xor(mx, o));
        float e = (lane < CC) ? __expf(x - mx) : 0.0f;
        float se = e;
        #pragma unroll
        for (int o = 32; o > 0; o >>= 1) se += __shfl_xor(se, o);
        const float lp = x - mx - __logf(se);
        const float lpe = __shfl(lp, ext_s);
        float newa;
        if (t == 0) {
            newa = (lane <= 1) ? lpe : NEG;
        } else {
            float a1 = __shfl_up(alpha, 1);
            if (lane == 0) a1 = NEG;
            float a2 = __shfl_up(alpha, 2);
            if (!skip_ok) a2 = NEG;
            newa = logaddexp_f(logaddexp_f(alpha, a1), a2) + lpe;
        }
        if (!valid) newa = NEG;
        alpha = newa;
        if (ilen == t + 1) {
            const float e1 = __shfl(alpha, end_idx);
            const float e2 = __shfl(alpha, end_idx - 1);
            final_v = logaddexp_f(e1, e2);
        }
    }
    if (lane == 0) per_sample[b] = -final_v / (float)tlen;
}

// ---------------- Deterministic mean over B samples ------------------------
__global__ __launch_bounds__(256) void reduce_mean_kernel(
    const float* __restrict__ ps, float* __restrict__ out, int B)
{
    float s = 0.0f;
    for (int i = threadIdx.x; i < B; i += 256) s += ps[i];
    #pragma unroll
    for (int o = 32; o > 0; o >>= 1) s += __shfl_xor(s, o);
    __shared__ float sm[4];
    const int w = threadIdx.x >> 6, l = threadIdx.x & 63;
    if (l == 0) sm[w] = s;
    __syncthreads();
    if (threadIdx.x == 0) {
        out[0] = (sm[0] + sm[1] + sm[2] + sm[3]) / (float)B;
    }
}

extern "C" void kernel_launch(void* const* d_in, const int* in_sizes, int n_in,
                              void* d_out, int out_size, void* d_ws, size_t ws_size,
                              hipStream_t stream) {
    const float* logits         = (const float*)d_in[0];
    const int*   targets        = (const int*)d_in[1];
    const int*   input_lengths  = (const int*)d_in[2];
    const int*   target_lengths = (const int*)d_in[3];

    const int B = in_sizes[2];
    const int L = in_sizes[1] / B;
    const int T = in_sizes[0] / (B * CC);
    const long long N = (long long)B * T;

    float* per_sample = (float*)d_ws;               // B floats
    float* scratch    = per_sample + B;             // trans OR denom
    float* out        = (float*)d_out;

    const size_t ws_fast = ((size_t)B + (size_t)B * CC * T) * sizeof(float);
    const size_t ws_mid  = ((size_t)B + (size_t)N) * sizeof(float);
    const int nblocks_alpha = (B * 64 + 255) / 256;
    const long long nwaves = (N + 63) / 64;

    if (ws_size >= ws_fast && (T % 64 == 0) && T >= 16) {
        lse_transpose_kernel<<<(int)((nwaves + 3) / 4), 256, 0, stream>>>(
            logits, scratch, T, N);
        ctc_alpha5_kernel<<<nblocks_alpha, 256, 0, stream>>>(
            scratch, targets, input_lengths, target_lengths, per_sample, B, T, L);
    } else if (ws_size >= ws_mid && T >= 2) {
        lse_kernel<<<(int)((nwaves + 3) / 4), 256, 0, stream>>>(logits, scratch, (int)N);
        ctc_alpha2_kernel<<<nblocks_alpha, 256, 0, stream>>>(
            logits, scratch, targets, input_lengths, target_lengths, per_sample, B, T, L);
    } else {
        ctc_alpha_mono_kernel<<<nblocks_alpha, 256, 0, stream>>>(
            logits, targets, input_lengths, target_lengths, per_sample, B, T, L);
    }
    reduce_mean_kernel<<<1, 256, 0, stream>>>(per_sample, out, B);
}

// Round 6
// 144.661 us; speedup vs baseline: 1.6845x; 1.1502x over previous
//
#include <hip/hip_runtime.h>

#define BLANK 36
#define NEG -1e30f
#define CC 37

__device__ __forceinline__ float logaddexp_f(float a, float b) {
    float m = fmaxf(a, b);
    float d = fabsf(a - b);
    return m + __logf(1.0f + __expf(-d));
}

// ============ FAST PATH: fully fused, one wave per sample ==================
// Chunked over T in blocks of 64 steps. Per-wave LDS double buffer:
//   X[2][64*37] raw logits chunk, D[2][64] per-row logsumexp.
// Pipeline per chunk c: (a) issue global float4 loads of chunk c+1 into
// registers (latency hidden by (b)); (b) 64 recurrence steps on chunk c,
// lpe read from LDS via a 4-step named-register lookahead (no dynamic
// indexing -> no scratch spill, the R4 failure); (c) ds_write staged regs,
// per-lane row softmax for chunk c+1 (off critical chain).
// LDS: 4 waves * 4992 floats = 79872 B -> 2 blocks/CU; B/4=512 blocks = 2/CU.
__global__ __launch_bounds__(256) void ctc_fused_kernel(
    const float* __restrict__ logits,        // [B, T, C]
    const int*   __restrict__ targets,       // [B * L]
    const int*   __restrict__ input_lengths, // [B]
    const int*   __restrict__ target_lengths,// [B]
    float*       __restrict__ per_sample,    // [B]
    int B, int T, int L)
{
    __shared__ float lds[4 * 4992];
    const int lane = threadIdx.x & 63;
    const int wib  = threadIdx.x >> 6;
    const int b    = blockIdx.x * 4 + wib;
    if (b >= B) return;

    float* X0 = lds + wib * 4992;     // 2368 floats
    float* X1 = X0 + 2368;            // 2368 floats
    float* D0 = X0 + 4736;            // 64 floats
    float* D1 = D0 + 64;              // 64 floats

    const int S = 2 * L + 1;
    const int tlen = target_lengths[b];
    const int ilen = input_lengths[b];
    const int end_idx = 2 * tlen;

    int ext_s = BLANK;                // < CC always -> LDS reads in-bounds
    if (lane < S && (lane & 1)) ext_s = targets[b * L + (lane >> 1)];
    const int ext_sm2 = __shfl_up(ext_s, 2);
    const bool skip_ok = (lane < S) && (lane >= 2) && (ext_s != BLANK) && (ext_s != ext_sm2);
    const bool valid = lane < (2 * tlen + 1);

    const float4* src = (const float4*)(logits + (size_t)b * T * CC);  // 16B-aligned

    float alpha = NEG, cap = NEG;

    auto STEP = [&](float lpe, int tt) {
        float a1 = __shfl_up(alpha, 1);
        a1 = (lane == 0) ? NEG : a1;
        float a2 = __shfl_up(alpha, 2);
        a2 = skip_ok ? a2 : NEG;
        const float mm = fmaxf(fmaxf(alpha, a1), a2);
        const float ss = __expf(alpha - mm) + __expf(a1 - mm) + __expf(a2 - mm);
        alpha = valid ? (mm + __logf(ss) + lpe) : NEG;
        cap = (ilen == tt + 1) ? alpha : cap;  // per-lane capture, off chain
    };

    // ---- prologue: stage + softmax chunk 0 ----
    {
        float4* dst = (float4*)X0;
        #pragma unroll
        for (int k = 0; k < 9; ++k) dst[k * 64 + lane] = src[k * 64 + lane];
        if (lane < 16) dst[576 + lane] = src[576 + lane];   // 592 = 9*64+16
        __builtin_amdgcn_s_waitcnt(0);
        const float* xr = X0 + lane * CC;
        float m = xr[0];
        #pragma unroll
        for (int c2 = 1; c2 < CC; ++c2) m = fmaxf(m, xr[c2]);
        float ss = 0.0f;
        #pragma unroll
        for (int c2 = 0; c2 < CC; ++c2) ss += __expf(xr[c2] - m);
        D0[lane] = m + __logf(ss);
        __builtin_amdgcn_s_waitcnt(0);
    }

    const int NC = T >> 6;            // chunks of 64 (T % 64 == 0 on this path)
    for (int c = 0; c < NC; ++c) {
        float* Xb = (c & 1) ? X1 : X0;
        float* Db = (c & 1) ? D1 : D0;
        const bool more = (c + 1 < NC);

        // (a) issue global loads for chunk c+1 (named regs; latency hidden by (b))
        float4 f0 = {}, f1 = {}, f2 = {}, f3 = {}, f4 = {},
               f5 = {}, f6 = {}, f7 = {}, f8 = {}, f9 = {};
        if (more) {
            const float4* s2 = src + (size_t)(c + 1) * 592;
            f0 = s2[lane];       f1 = s2[64 + lane];  f2 = s2[128 + lane];
            f3 = s2[192 + lane]; f4 = s2[256 + lane]; f5 = s2[320 + lane];
            f6 = s2[384 + lane]; f7 = s2[448 + lane]; f8 = s2[512 + lane];
            if (lane < 16) f9 = s2[576 + lane];
        }

        // (b) 64 recurrence steps with 4-step lookahead from LDS
        const int tbase = c << 6;
        float p0 = Xb[0 * CC + ext_s] - Db[0];
        float p1 = Xb[1 * CC + ext_s] - Db[1];
        float p2 = Xb[2 * CC + ext_s] - Db[2];
        float p3 = Xb[3 * CC + ext_s] - Db[3];
        float q0, q1, q2, q3;
        int g = 0;
        if (c == 0) {                 // t = 0 init peeled
            alpha = (valid && lane <= 1) ? p0 : NEG;
            cap = (ilen == 1) ? alpha : cap;
            q0 = Xb[4 * CC + ext_s] - Db[4];
            q1 = Xb[5 * CC + ext_s] - Db[5];
            q2 = Xb[6 * CC + ext_s] - Db[6];
            q3 = Xb[7 * CC + ext_s] - Db[7];
            STEP(p1, 1); STEP(p2, 2); STEP(p3, 3);
            p0 = q0; p1 = q1; p2 = q2; p3 = q3;
            g = 1;
        }
        for (; g < 16; ++g) {
            const int r = (g + 1) << 2;
            if (g < 15) {
                q0 = Xb[(r + 0) * CC + ext_s] - Db[r + 0];
                q1 = Xb[(r + 1) * CC + ext_s] - Db[r + 1];
                q2 = Xb[(r + 2) * CC + ext_s] - Db[r + 2];
                q3 = Xb[(r + 3) * CC + ext_s] - Db[r + 3];
            }
            const int tt = tbase + (g << 2);
            STEP(p0, tt); STEP(p1, tt + 1); STEP(p2, tt + 2); STEP(p3, tt + 3);
            p0 = q0; p1 = q1; p2 = q2; p3 = q3;
        }

        // (c) commit staged chunk c+1 + its softmax
        if (more) {
            float* Xn = (c & 1) ? X0 : X1;
            float* Dn = (c & 1) ? D0 : D1;
            float4* dst = (float4*)Xn;
            dst[lane] = f0;       dst[64 + lane] = f1;  dst[128 + lane] = f2;
            dst[192 + lane] = f3; dst[256 + lane] = f4; dst[320 + lane] = f5;
            dst[384 + lane] = f6; dst[448 + lane] = f7; dst[512 + lane] = f8;
            if (lane < 16) dst[576 + lane] = f9;
            __builtin_amdgcn_s_waitcnt(0);
            const float* xr = Xn + lane * CC;
            float m = xr[0];
            #pragma unroll
            for (int c2 = 1; c2 < CC; ++c2) m = fmaxf(m, xr[c2]);
            float ss = 0.0f;
            #pragma unroll
            for (int c2 = 0; c2 < CC; ++c2) ss += __expf(xr[c2] - m);
            Dn[lane] = m + __logf(ss);
            __builtin_amdgcn_s_waitcnt(0);
        }
    }

    const float e1 = __shfl(cap, end_idx);
    const float e2 = __shfl(cap, end_idx - 1);
    const float final_v = logaddexp_f(e1, e2);
    if (lane == 0) per_sample[b] = -final_v / (float)tlen;
}

// ============ FALLBACK PATH (proven R2 kernels) ============================
__global__ __launch_bounds__(256) void lse_kernel(
    const float* __restrict__ logits, float* __restrict__ denom, int N)
{
    __shared__ float lds[256 * CC];
    const int lane = threadIdx.x & 63;
    const int wib  = threadIdx.x >> 6;
    const int wave = blockIdx.x * 4 + wib;
    const long long row0 = (long long)wave * 64;
    if (row0 >= N) return;
    const int wbase = wib * 64 * CC;
    const float4* src4 = (const float4*)(logits + row0 * CC);
    const long long n4_remaining = ((long long)N * CC - row0 * CC) / 4;
    float4* lds4 = (float4*)(lds + wbase);
    #pragma unroll
    for (int k = 0; k < 10; ++k) {
        const int idx = k * 64 + lane;
        if (idx < 592 && idx < n4_remaining) lds4[idx] = src4[idx];
    }
    __builtin_amdgcn_s_waitcnt(0);
    const long long row = row0 + lane;
    if (row >= N) return;
    const float* x = lds + wbase + lane * CC;
    float m = x[0];
    #pragma unroll
    for (int c = 1; c < CC; ++c) m = fmaxf(m, x[c]);
    float s = 0.0f;
    #pragma unroll
    for (int c = 0; c < CC; ++c) s += __expf(x[c] - m);
    denom[row] = m + __logf(s);
}

__global__ __launch_bounds__(256) void ctc_alpha2_kernel(
    const float* __restrict__ logits, const float* __restrict__ denom,
    const int* __restrict__ targets, const int* __restrict__ input_lengths,
    const int* __restrict__ target_lengths, float* __restrict__ per_sample,
    int B, int T, int L)
{
    const int wave = (int)((blockIdx.x * blockDim.x + threadIdx.x) >> 6);
    const int lane = threadIdx.x & 63;
    if (wave >= B) return;
    const int b = wave;
    const int S = 2 * L + 1;
    const int tlen = target_lengths[b];
    const int ilen = input_lengths[b];
    const int end_idx = 2 * tlen;
    int ext_s = BLANK;
    if (lane < S && (lane & 1)) ext_s = targets[b * L + (lane >> 1)];
    const int ext_sm2 = __shfl_up(ext_s, 2);
    const bool skip_ok = (lane < S) && (lane >= 2) && (ext_s != BLANK) && (ext_s != ext_sm2);
    const bool valid = lane < (2 * tlen + 1);
    const float* lg = logits + (size_t)b * T * CC;
    const float* dn = denom + (size_t)b * T;
    float x_cur = lg[ext_s];
    float d_cur = dn[0];
    float x_nx = (T > 1) ? lg[CC + ext_s] : 0.0f;
    float d_nx = (T > 1) ? dn[1] : 0.0f;
    float final_v = NEG;
    float alpha = (valid && lane <= 1) ? (x_cur - d_cur) : NEG;
    if (ilen == 1) {
        const float e1 = __shfl(alpha, end_idx);
        const float e2 = __shfl(alpha, end_idx - 1);
        final_v = logaddexp_f(e1, e2);
    }
    for (int tt = 1; tt < T; ++tt) {
        x_cur = x_nx; d_cur = d_nx;
        if (tt + 1 < T) {
            x_nx = lg[(size_t)(tt + 1) * CC + ext_s];
            d_nx = dn[tt + 1];
        }
        const float lpe = x_cur - d_cur;
        float a1 = __shfl_up(alpha, 1);
        if (lane == 0) a1 = NEG;
        float a2 = __shfl_up(alpha, 2);
        if (!skip_ok) a2 = NEG;
        const float m = fmaxf(fmaxf(alpha, a1), a2);
        const float s = __expf(alpha - m) + __expf(a1 - m) + __expf(a2 - m);
        const float na = m + __logf(s) + lpe;
        alpha = valid ? na : NEG;
        if (ilen == tt + 1) {
            const float e1 = __shfl(alpha, end_idx);
            const float e2 = __shfl(alpha, end_idx - 1);
            final_v = logaddexp_f(e1, e2);
        }
    }
    if (lane == 0) per_sample[b] = -final_v / (float)tlen;
}

__global__ __launch_bounds__(256) void ctc_alpha_mono_kernel(
    const float* __restrict__ logits, const int* __restrict__ targets,
    const int* __restrict__ input_lengths, const int* __restrict__ target_lengths,
    float* __restrict__ per_sample, int B, int T, int L)
{
    const int wave = (int)((blockIdx.x * blockDim.x + threadIdx.x) >> 6);
    const int lane = threadIdx.x & 63;
    if (wave >= B) return;
    const int b = wave;
    const int S = 2 * L + 1;
    const int tlen = target_lengths[b];
    const int ilen = input_lengths[b];
    const int end_idx = 2 * tlen;
    int ext_s = BLANK;
    if (lane < S && (lane & 1)) ext_s = targets[b * L + (lane >> 1)];
    const int ext_sm2 = __shfl_up(ext_s, 2);
    const bool skip_ok = (lane < S) && (lane >= 2) && (ext_s != BLANK) && (ext_s != ext_sm2);
    const bool valid = lane < (2 * tlen + 1);
    const float* lg = logits + (size_t)b * T * CC;
    float alpha = NEG, final_v = NEG;
    for (int t = 0; t < T; ++t) {
        float x = (lane < CC) ? lg[t * CC + lane] : -3.0e38f;
        float mx = x;
        #pragma unroll
        for (int o = 32; o > 0; o >>= 1) mx = fmaxf(mx, __shfl_xor(mx, o));
        float e = (lane < CC) ? __expf(x - mx) : 0.0f;
        float se = e;
        #pragma unroll
        for (int o = 32; o > 0; o >>= 1) se += __shfl_xor(se, o);
        const float lp = x - mx - __logf(se);
        const float lpe = __shfl(lp, ext_s);
        float newa;
        if (t == 0) {
            newa = (lane <= 1) ? lpe : NEG;
        } else {
            float a1 = __shfl_up(alpha, 1);
            if (lane == 0) a1 = NEG;
            float a2 = __shfl_up(alpha, 2);
            if (!skip_ok) a2 = NEG;
            newa = logaddexp_f(logaddexp_f(alpha, a1), a2) + lpe;
        }
        if (!valid) newa = NEG;
        alpha = newa;
        if (ilen == t + 1) {
            const float e1 = __shfl(alpha, end_idx);
            const float e2 = __shfl(alpha, end_idx - 1);
            final_v = logaddexp_f(e1, e2);
        }
    }
    if (lane == 0) per_sample[b] = -final_v / (float)tlen;
}

// ---------------- Deterministic mean over B samples ------------------------
__global__ __launch_bounds__(256) void reduce_mean_kernel(
    const float* __restrict__ ps, float* __restrict__ out, int B)
{
    float s = 0.0f;
    for (int i = threadIdx.x; i < B; i += 256) s += ps[i];
    #pragma unroll
    for (int o = 32; o > 0; o >>= 1) s += __shfl_xor(s, o);
    __shared__ float sm[4];
    const int w = threadIdx.x >> 6, l = threadIdx.x & 63;
    if (l == 0) sm[w] = s;
    __syncthreads();
    if (threadIdx.x == 0) {
        out[0] = (sm[0] + sm[1] + sm[2] + sm[3]) / (float)B;
    }
}

extern "C" void kernel_launch(void* const* d_in, const int* in_sizes, int n_in,
                              void* d_out, int out_size, void* d_ws, size_t ws_size,
                              hipStream_t stream) {
    const float* logits         = (const float*)d_in[0];
    const int*   targets        = (const int*)d_in[1];
    const int*   input_lengths  = (const int*)d_in[2];
    const int*   target_lengths = (const int*)d_in[3];

    const int B = in_sizes[2];
    const int L = in_sizes[1] / B;
    const int T = in_sizes[0] / (B * CC);
    const long long N = (long long)B * T;

    float* per_sample = (float*)d_ws;               // B floats
    float* scratch    = per_sample + B;             // denom (fallback only)
    float* out        = (float*)d_out;

    const size_t ws_mid = ((size_t)B + (size_t)N) * sizeof(float);
    const int nblocks_alpha = (B * 64 + 255) / 256;
    const long long nwaves = (N + 63) / 64;

    if ((T % 64 == 0) && T >= 64 && L <= 31 && ws_size >= (size_t)B * sizeof(float)) {
        ctc_fused_kernel<<<(B + 3) / 4, 256, 0, stream>>>(
            logits, targets, input_lengths, target_lengths, per_sample, B, T, L);
    } else if (ws_size >= ws_mid && T >= 2) {
        lse_kernel<<<(int)((nwaves + 3) / 4), 256, 0, stream>>>(logits, scratch, (int)N);
        ctc_alpha2_kernel<<<nblocks_alpha, 256, 0, stream>>>(
            logits, scratch, targets, input_lengths, target_lengths, per_sample, B, T, L);
    } else {
        ctc_alpha_mono_kernel<<<nblocks_alpha, 256, 0, stream>>>(
            logits, targets, input_lengths, target_lengths, per_sample, B, T, L);
    }
    reduce_mean_kernel<<<1, 256, 0, stream>>>(per_sample, out, B);
}